// Round 3
// baseline (3483.388 us; speedup 1.0000x reference)
//
#include <hip/hip_runtime.h>
#include <hip/hip_bf16.h>
#include <math.h>

#define D_EMB 2048
#define NH 16
#define DK 128
#define SEQN 128
#define DFF 8192
#define VOCAB 30000
#define NLAYERS 6
#define TOKF (SEQN * D_EMB)   // 262144 elements

typedef __attribute__((ext_vector_type(8))) short short8v;
typedef __attribute__((ext_vector_type(4))) float float4v;
typedef __hip_bfloat16 bf16;

#define GLOAD_LDS16(g, l)                                                      \
    __builtin_amdgcn_global_load_lds(                                          \
        (const __attribute__((address_space(1))) void*)(g),                    \
        (__attribute__((address_space(3))) void*)(l), 16, 0, 0)

#define WAIT_BAR(n)                                                            \
    do {                                                                       \
        asm volatile("s_waitcnt vmcnt(" #n ")" ::: "memory");                  \
        __builtin_amdgcn_s_barrier();                                          \
        asm volatile("" ::: "memory");                                         \
    } while (0)

struct MegaArgs {
    const float *x7, *ctx7;
    const float *Wq1, *Wk1, *Wv1, *Wo1, *Wq2, *Wk2, *Wv2, *Wo2;
    const float *W_ff1, *b_ff1, *W_ff2, *b_ff2;
    const float *g1, *be1, *g2, *be2, *g3, *be3;
    const float *W_lin;
    float *out;
    bf16 *wq1, *wk1, *wv1, *wo1, *wq2, *wk2, *wv2, *wo2, *wff1, *wff2, *wctx;
    bf16 *X, *Att, *H;
    float *Qp, *Kp, *Vp, *X2p, *K2p, *V2p, *FFp;
};

// ---------------------------------------------------------------------------
// Device-wide sense-reversing barrier. Safe because grid <= guaranteed
// co-resident capacity (128 KB static LDS -> 1 block/CU, grid <= #CU).
// __threadfence() provides device-scope release/acquire (L2 wb/inv) so data
// written before the barrier is visible across XCDs after it.
// ---------------------------------------------------------------------------
__device__ __forceinline__ void gsync(unsigned* cnt, unsigned* gen) {
    __syncthreads();                       // drains vmcnt/lgkmcnt for all waves
    if (threadIdx.x == 0) {
        __threadfence();                   // release: flush this XCD's L2
        unsigned g = __hip_atomic_load(gen, __ATOMIC_RELAXED, __HIP_MEMORY_SCOPE_AGENT);
        unsigned nblk = gridDim.x;
        if (__hip_atomic_fetch_add(cnt, 1u, __ATOMIC_ACQ_REL, __HIP_MEMORY_SCOPE_AGENT)
            == nblk - 1u) {
            __hip_atomic_store(cnt, 0u, __ATOMIC_RELAXED, __HIP_MEMORY_SCOPE_AGENT);
            __hip_atomic_store(gen, g + 1u, __ATOMIC_RELEASE, __HIP_MEMORY_SCOPE_AGENT);
        } else {
            while (__hip_atomic_load(gen, __ATOMIC_RELAXED, __HIP_MEMORY_SCOPE_AGENT) == g)
                __builtin_amdgcn_s_sleep(8);
        }
        __threadfence();                   // acquire: invalidate stale lines
    }
    __syncthreads();
}

__device__ __forceinline__ short4 pack4(float a, float b, float c, float d) {
    union { short4 s4; bf16 h[4]; } u;
    u.h[0] = __float2bfloat16(a); u.h[1] = __float2bfloat16(b);
    u.h[2] = __float2bfloat16(c); u.h[3] = __float2bfloat16(d);
    return u.s4;
}

// ---------------------------------------------------------------------------
// fp32 -> bf16 segment convert, grid-stride, 4-deep ILP.
// ---------------------------------------------------------------------------
__device__ void cvt_seg(const float* __restrict__ src, bf16* __restrict__ dst,
                        int n4, int gid, int gstride) {
    const float4* s = (const float4*)src;
    short4* d = (short4*)dst;
    int i = gid;
    for (; i + 3 * gstride < n4; i += 4 * gstride) {
        float4 v0 = s[i];
        float4 v1 = s[i + gstride];
        float4 v2 = s[i + 2 * gstride];
        float4 v3 = s[i + 3 * gstride];
        d[i]               = pack4(v0.x, v0.y, v0.z, v0.w);
        d[i + gstride]     = pack4(v1.x, v1.y, v1.z, v1.w);
        d[i + 2 * gstride] = pack4(v2.x, v2.y, v2.z, v2.w);
        d[i + 3 * gstride] = pack4(v3.x, v3.y, v3.z, v3.w);
    }
    for (; i < n4; i += gstride) {
        float4 v = s[i];
        d[i] = pack4(v.x, v.y, v.z, v.w);
    }
}

// x[7] + sinusoidal PE -> X bf16
__device__ void pe_seg(const float* __restrict__ x7, bf16* __restrict__ X,
                       int gid, int gstride) {
    for (int i4 = gid; i4 < TOKF / 4; i4 += gstride) {
        int idx = i4 << 2;
        int l = idx >> 11;
        int d = idx & 2047;
        float4 xv = ((const float4*)x7)[i4];
        float div0 = __expf(-9.210340371976184f * ((float)d * (1.0f / 2048.0f)));
        float div1 = __expf(-9.210340371976184f * ((float)(d + 2) * (1.0f / 2048.0f)));
        float a0 = (float)l * div0, a1 = (float)l * div1;
        ((short4*)X)[i4] = pack4(xv.x + sinf(a0), xv.y + cosf(a0),
                                 xv.z + sinf(a1), xv.w + cosf(a1));
    }
}

// ---------------------------------------------------------------------------
// GEMM job: C(fp32 partial) = A[64 rows] @ B[64 rows]^T over Klocal=512.
// One-shot 128 KB LDS stage, counted vmcnt, 4 raw barriers. (R2-proven body.)
// ---------------------------------------------------------------------------
__device__ __forceinline__ void gemm_job(char* smem, const bf16* __restrict__ A,
                                         const bf16* __restrict__ B,
                                         float* __restrict__ C,
                                         int N, int K, int kbase, int m0, int n0) {
    char* AsB = smem;            // 4 chunks x 16 KB
    char* BsB = smem + 65536;

    int tid = threadIdx.x;
    int w = tid >> 6;
    int lane = tid & 63;
    int wm = (w & 1) * 32;
    int wn = (w >> 1) * 32;
    int fcol = lane & 15;
    int fqu  = lane >> 4;
    int rr   = (w << 2) + (lane >> 4);
    int scol = lane & 15;

    float4v acc[2][2];
    acc[0][0] = (float4v)0.0f; acc[0][1] = (float4v)0.0f;
    acc[1][0] = (float4v)0.0f; acc[1][1] = (float4v)0.0f;

    #pragma unroll
    for (int c = 0; c < 4; ++c) {
        const bf16* a0 = A + (size_t)m0 * K + kbase + (c << 7);
        const bf16* b0 = B + (size_t)n0 * K + kbase + (c << 7);
        #pragma unroll
        for (int t = 0; t < 4; ++t) {
            int r = t * 16 + rr;
            int s = scol ^ (r & 15);
            GLOAD_LDS16(a0 + (size_t)r * K + s * 8,
                        AsB + (size_t)c * 16384 + (size_t)(t * 16 + (w << 2)) * 256);
            GLOAD_LDS16(b0 + (size_t)r * K + s * 8,
                        BsB + (size_t)c * 16384 + (size_t)(t * 16 + (w << 2)) * 256);
        }
    }

    auto compute_chunk = [&](int c) {
        const char* Ac = AsB + (size_t)c * 16384;
        const char* Bc = BsB + (size_t)c * 16384;
        #pragma unroll
        for (int kk = 0; kk < 4; ++kk) {
            short8v a[2], b[2];
            int slog = kk * 4 + fqu;
            #pragma unroll
            for (int fm = 0; fm < 2; ++fm) {
                int m = wm + fm * 16 + fcol;
                a[fm] = *(const short8v*)(Ac + m * 256 + ((slog ^ (m & 15)) << 4));
            }
            #pragma unroll
            for (int fn = 0; fn < 2; ++fn) {
                int n = wn + fn * 16 + fcol;
                b[fn] = *(const short8v*)(Bc + n * 256 + ((slog ^ (n & 15)) << 4));
            }
            #pragma unroll
            for (int fm = 0; fm < 2; ++fm)
                #pragma unroll
                for (int fn = 0; fn < 2; ++fn)
                    acc[fm][fn] = __builtin_amdgcn_mfma_f32_16x16x32_bf16(
                        a[fm], b[fn], acc[fm][fn], 0, 0, 0);
        }
    };

    WAIT_BAR(24); compute_chunk(0);
    WAIT_BAR(16); compute_chunk(1);
    WAIT_BAR(8);  compute_chunk(2);
    WAIT_BAR(0);  compute_chunk(3);

    int rbase = fqu * 4;
    #pragma unroll
    for (int fm = 0; fm < 2; ++fm)
        #pragma unroll
        for (int fn = 0; fn < 2; ++fn) {
            int n = n0 + wn + fn * 16 + fcol;
            #pragma unroll
            for (int r = 0; r < 4; ++r) {
                int m = m0 + wm + fm * 16 + rbase + r;
                C[(size_t)m * N + n] = acc[fm][fn][r];
            }
        }
    __syncthreads();   // LDS reuse fence for the next job in this phase
}

__device__ void gemm_phase(char* smem, const bf16* A,
                           const bf16* B0, const bf16* B1, const bf16* B2,
                           float* C0, float* C1, float* C2,
                           int M, int N, int K, int kslog, int nout,
                           int bid, int nblk) {
    int MB = M >> 6, NB = N >> 6;
    int ksplit = 1 << kslog;
    int njobs = MB * NB * nout * ksplit;
    for (int job = bid; job < njobs; job += nblk) {
        int bx = job % MB;
        int r1 = job / MB;
        int by = r1 % NB;
        int bz = r1 / NB;
        int oi = bz >> kslog;
        int kh = bz & (ksplit - 1);
        const bf16* B = (oi == 0) ? B0 : (oi == 1) ? B1 : B2;
        float* C = (oi == 0) ? C0 : (oi == 1) ? C1 : C2;
        gemm_job(smem, A, B, C + (size_t)kh * M * N, N, K, kh << 9, bx << 6, by << 6);
    }
}

// ---------------------------------------------------------------------------
// Per-token "attention" (faithful bug). qparts = kvparts = 4 hardcoded.
// ---------------------------------------------------------------------------
__device__ void attn_job(char* smem, const float* __restrict__ qp,
                         const float* __restrict__ kp, const float* __restrict__ vp,
                         bf16* __restrict__ O, int causal, int l) {
    int tid = threadIdx.x;
    int i = tid & 127;
    int half = tid >> 7;
    float* qs = (float*)smem;                       // 2048 f
    float* ks = qs + D_EMB;
    float* vs = ks + D_EMB;
    float* m1s = vs + D_EMB;                        // 128
    float* l1s = m1s + 128;
    float (*acc1s)[NH + 1] = (float(*)[NH + 1])(l1s + 128);
    size_t base = (size_t)l * D_EMB;

    for (int d4 = tid; d4 < D_EMB / 4; d4 += 256) {
        float4 q = {0, 0, 0, 0}, kv = {0, 0, 0, 0}, vv = {0, 0, 0, 0};
        #pragma unroll
        for (int p = 0; p < 4; ++p) {
            float4 t = ((const float4*)(qp + (size_t)p * TOKF + base))[d4];
            q.x += t.x; q.y += t.y; q.z += t.z; q.w += t.w;
            float4 u = ((const float4*)(kp + (size_t)p * TOKF + base))[d4];
            kv.x += u.x; kv.y += u.y; kv.z += u.z; kv.w += u.w;
            float4 s = ((const float4*)(vp + (size_t)p * TOKF + base))[d4];
            vv.x += s.x; vv.y += s.y; vv.z += s.z; vv.w += s.w;
        }
        ((float4*)qs)[d4] = q;
        ((float4*)ks)[d4] = kv;
        ((float4*)vs)[d4] = vv;
    }
    __syncthreads();

    const float scale = 0.088388347648318447f;  // 1/sqrt(128)
    float qr[NH];
    #pragma unroll
    for (int h = 0; h < NH; ++h) qr[h] = qs[h * DK + i];

    int jmax = causal ? (i + 1) : DK;
    int j0 = half * 64;
    int j1 = (jmax < j0 + 64) ? jmax : (j0 + 64);

    float m = -INFINITY, lsum = 0.0f;
    float acc[NH];
    #pragma unroll
    for (int h = 0; h < NH; ++h) acc[h] = 0.0f;

    for (int j = j0; j < j1; j += 4) {
        float4 s4 = {0, 0, 0, 0};
        #pragma unroll
        for (int h = 0; h < NH; ++h) {
            float4 kv = *(const float4*)&ks[h * DK + j];
            s4.x += qr[h] * kv.x; s4.y += qr[h] * kv.y;
            s4.z += qr[h] * kv.z; s4.w += qr[h] * kv.w;
        }
        float sv0 = s4.x * scale;
        float sv1 = (j + 1 < j1) ? s4.y * scale : -INFINITY;
        float sv2 = (j + 2 < j1) ? s4.z * scale : -INFINITY;
        float sv3 = (j + 3 < j1) ? s4.w * scale : -INFINITY;
        float mx = fmaxf(fmaxf(sv0, sv1), fmaxf(sv2, sv3));
        float nm = fmaxf(m, mx);
        float f  = __expf(m - nm);
        float p0 = __expf(sv0 - nm);
        float p1 = __expf(sv1 - nm);
        float p2 = __expf(sv2 - nm);
        float p3 = __expf(sv3 - nm);
        lsum = lsum * f + ((p0 + p1) + (p2 + p3));
        #pragma unroll
        for (int h = 0; h < NH; ++h) {
            float4 vv = *(const float4*)&vs[h * DK + j];
            acc[h] = acc[h] * f + ((p0 * vv.x + p1 * vv.y) + (p2 * vv.z + p3 * vv.w));
        }
        m = nm;
    }

    if (half) {
        m1s[i] = m; l1s[i] = lsum;
        #pragma unroll
        for (int h = 0; h < NH; ++h) acc1s[i][h] = acc[h];
    }
    __syncthreads();
    if (!half) {
        float m1 = m1s[i], l1 = l1s[i];
        float nm = fmaxf(m, m1);
        float f0 = __expf(m - nm);
        float f1 = __expf(m1 - nm);
        float rinv = 1.0f / (lsum * f0 + l1 * f1);
        #pragma unroll
        for (int h = 0; h < NH; ++h)
            O[base + h * DK + i] =
                __float2bfloat16((acc[h] * f0 + acc1s[i][h] * f1) * rinv);
    }
    __syncthreads();
}

// ---------------------------------------------------------------------------
// LayerNorm over sum of NPARTS fp32 partials (+ optional bias), bf16 out.
// ---------------------------------------------------------------------------
template<int NPARTS>
__device__ void ln_job(char* smem, const float* __restrict__ parts,
                       const float* __restrict__ addb, const float* __restrict__ g,
                       const float* __restrict__ b, bf16* __restrict__ Y, int row) {
    float4* vs4 = (float4*)smem;            // 512 f4 = 8 KB
    float* buf = (float*)(smem + 8192);
    int tid = threadIdx.x;
    size_t base = (size_t)row * D_EMB;

    float s = 0.0f;
    for (int d4 = tid; d4 < D_EMB / 4; d4 += 256) {
        float4 v = {0, 0, 0, 0};
        if (addb) v = ((const float4*)addb)[d4];
        #pragma unroll
        for (int p = 0; p < NPARTS; ++p) {
            float4 t = ((const float4*)(parts + (size_t)p * TOKF + base))[d4];
            v.x += t.x; v.y += t.y; v.z += t.z; v.w += t.w;
        }
        vs4[d4] = v;
        s += (v.x + v.y) + (v.z + v.w);
    }
    buf[tid] = s; __syncthreads();
    for (int off = 128; off; off >>= 1) {
        if (tid < off) buf[tid] += buf[tid + off];
        __syncthreads();
    }
    float mean = buf[0] * (1.0f / D_EMB);
    __syncthreads();

    float vsum = 0.0f;
    for (int d4 = tid; d4 < D_EMB / 4; d4 += 256) {
        float4 v = vs4[d4];
        float t0 = v.x - mean, t1 = v.y - mean, t2 = v.z - mean, t3 = v.w - mean;
        vsum += (t0 * t0 + t1 * t1) + (t2 * t2 + t3 * t3);
    }
    buf[tid] = vsum; __syncthreads();
    for (int off = 128; off; off >>= 1) {
        if (tid < off) buf[tid] += buf[tid + off];
        __syncthreads();
    }
    float inv = rsqrtf(buf[0] * (1.0f / D_EMB) + 1e-5f);

    for (int d4 = tid; d4 < D_EMB / 4; d4 += 256) {
        float4 v = vs4[d4];
        float4 g4 = ((const float4*)g)[d4];
        float4 b4 = ((const float4*)b)[d4];
        ((short4*)(Y + base))[d4] = pack4(g4.x * (v.x - mean) * inv + b4.x,
                                          g4.y * (v.y - mean) * inv + b4.y,
                                          g4.z * (v.z - mean) * inv + b4.z,
                                          g4.w * (v.w - mean) * inv + b4.w);
    }
    __syncthreads();
}

// sum 4 fp32 partials + bias + relu -> bf16 H (FFN1 epilogue)
__device__ void biasrelu_phase(const float* __restrict__ P, const float* __restrict__ bias,
                               bf16* __restrict__ H, int gid, int gstride) {
    const int n4 = SEQN * DFF / 4;
    const float4* p = (const float4*)P;
    for (int i4 = gid; i4 < n4; i4 += gstride) {
        float4 v0 = p[i4];
        float4 v1 = p[i4 + n4];
        float4 v2 = p[i4 + 2 * n4];
        float4 v3 = p[i4 + 3 * n4];
        float4 b4 = ((const float4*)bias)[i4 & (DFF / 4 - 1)];
        ((short4*)H)[i4] = pack4(fmaxf(v0.x + v1.x + v2.x + v3.x + b4.x, 0.0f),
                                 fmaxf(v0.y + v1.y + v2.y + v3.y + b4.y, 0.0f),
                                 fmaxf(v0.z + v1.z + v2.z + v3.z + b4.z, 0.0f),
                                 fmaxf(v0.w + v1.w + v2.w + v3.w + b4.w, 0.0f));
    }
}

// ---------------------------------------------------------------------------
// Fused logits GEMM + sequence-axis softmax (faithful bug), with W fp32
// register prefetch pipeline (counted vmcnt, raw barriers).
// ---------------------------------------------------------------------------
__device__ void logits_job(char* smem, const bf16* __restrict__ X,
                           const float* __restrict__ W, float* __restrict__ out,
                           int n0) {
    char* AsB = smem;                     // 32 KB
    char* BsB = smem + 32768;             // 16 KB
    float (*red)[64] = (float(*)[64])(smem + 49152);

    int tid = threadIdx.x;
    int w = tid >> 6;
    int lane = tid & 63;
    int fcol = lane & 15;
    int fqu  = lane >> 4;

    float4v acc[2][4];
    #pragma unroll
    for (int fm = 0; fm < 2; ++fm)
        #pragma unroll
        for (int fn = 0; fn < 4; ++fn) acc[fm][fn] = (float4v)0.0f;

    int brow = tid >> 2;
    int q    = tid & 3;
    int gn   = n0 + brow;
    const float* gpbase = W + (size_t)gn * D_EMB;

    float4 wreg[8];
    auto loadW = [&](int k0) {
        if (gn < VOCAB) {
            #pragma unroll
            for (int j = 0; j < 4; ++j) {
                const float* gp = gpbase + k0 + (q * 4 + j) * 8;
                wreg[2 * j]     = *(const float4*)gp;
                wreg[2 * j + 1] = *(const float4*)(gp + 4);
            }
        }
    };
    loadW(0);

    for (int k0i = 0; k0i < 16; ++k0i) {
        int k0 = k0i << 7;
        #pragma unroll
        for (int t = 0; t < 8; ++t) {
            int r = t * 16 + (w << 2) + (lane >> 4);
            int s = (lane & 15) ^ (r & 15);
            GLOAD_LDS16(X + (size_t)r * D_EMB + k0 + s * 8,
                        AsB + (size_t)(t * 16 + (w << 2)) * 256);
        }
        #pragma unroll
        for (int j = 0; j < 4; ++j) {
            int sL = q * 4 + j;
            union { short8v v; bf16 h[8]; } u;
            if (gn < VOCAB) {
                float4 f0 = wreg[2 * j], f1 = wreg[2 * j + 1];
                u.h[0] = __float2bfloat16(f0.x); u.h[1] = __float2bfloat16(f0.y);
                u.h[2] = __float2bfloat16(f0.z); u.h[3] = __float2bfloat16(f0.w);
                u.h[4] = __float2bfloat16(f1.x); u.h[5] = __float2bfloat16(f1.y);
                u.h[6] = __float2bfloat16(f1.z); u.h[7] = __float2bfloat16(f1.w);
            } else {
                u.v = (short8v)0;
            }
            *(short8v*)(BsB + brow * 256 + ((sL ^ (brow & 15)) << 4)) = u.v;
        }
        if (k0i < 15) {
            loadW(k0 + 128);            // prefetch hides HBM under MFMA
            asm volatile("s_waitcnt vmcnt(8) lgkmcnt(0)" ::: "memory");
        } else {
            asm volatile("s_waitcnt vmcnt(0) lgkmcnt(0)" ::: "memory");
        }
        __builtin_amdgcn_s_barrier();
        asm volatile("" ::: "memory");

        #pragma unroll
        for (int kk = 0; kk < 4; ++kk) {
            int slog = kk * 4 + fqu;
            short8v a[2], b[4];
            #pragma unroll
            for (int fm = 0; fm < 2; ++fm) {
                int m = w * 32 + fm * 16 + fcol;
                a[fm] = *(const short8v*)(AsB + m * 256 + ((slog ^ (m & 15)) << 4));
            }
            #pragma unroll
            for (int fn = 0; fn < 4; ++fn) {
                int n = fn * 16 + fcol;
                b[fn] = *(const short8v*)(BsB + n * 256 + ((slog ^ (n & 15)) << 4));
            }
            #pragma unroll
            for (int fm = 0; fm < 2; ++fm)
                #pragma unroll
                for (int fn = 0; fn < 4; ++fn)
                    acc[fm][fn] = __builtin_amdgcn_mfma_f32_16x16x32_bf16(
                        a[fm], b[fn], acc[fm][fn], 0, 0, 0);
        }
        asm volatile("" ::: "memory");
        __builtin_amdgcn_s_barrier();
    }

    float cmax[4];
    #pragma unroll
    for (int fn = 0; fn < 4; ++fn) {
        float m = -INFINITY;
        #pragma unroll
        for (int fm = 0; fm < 2; ++fm)
            #pragma unroll
            for (int r = 0; r < 4; ++r) m = fmaxf(m, acc[fm][fn][r]);
        m = fmaxf(m, __shfl_xor(m, 16));
        m = fmaxf(m, __shfl_xor(m, 32));
        cmax[fn] = m;
    }
    if (lane < 16) {
        #pragma unroll
        for (int fn = 0; fn < 4; ++fn) red[w][fn * 16 + lane] = cmax[fn];
    }
    __syncthreads();
    #pragma unroll
    for (int fn = 0; fn < 4; ++fn) {
        float m = red[0][fn * 16 + fcol];
        m = fmaxf(m, red[1][fn * 16 + fcol]);
        m = fmaxf(m, red[2][fn * 16 + fcol]);
        m = fmaxf(m, red[3][fn * 16 + fcol]);
        cmax[fn] = m;
    }
    __syncthreads();

    float csum[4];
    #pragma unroll
    for (int fn = 0; fn < 4; ++fn) {
        float s = 0.0f;
        #pragma unroll
        for (int fm = 0; fm < 2; ++fm)
            #pragma unroll
            for (int r = 0; r < 4; ++r) {
                float e = __expf(acc[fm][fn][r] - cmax[fn]);
                acc[fm][fn][r] = e;
                s += e;
            }
        s += __shfl_xor(s, 16);
        s += __shfl_xor(s, 32);
        csum[fn] = s;
    }
    if (lane < 16) {
        #pragma unroll
        for (int fn = 0; fn < 4; ++fn) red[w][fn * 16 + lane] = csum[fn];
    }
    __syncthreads();
    #pragma unroll
    for (int fn = 0; fn < 4; ++fn) {
        float s = red[0][fn * 16 + fcol] + red[1][fn * 16 + fcol]
                + red[2][fn * 16 + fcol] + red[3][fn * 16 + fcol];
        float rinv = 1.0f / s;
        int c = n0 + fn * 16 + fcol;
        if (c < VOCAB) {
            #pragma unroll
            for (int fm = 0; fm < 2; ++fm)
                #pragma unroll
                for (int r = 0; r < 4; ++r) {
                    int rw = w * 32 + fm * 16 + fqu * 4 + r;
                    out[(size_t)rw * VOCAB + c] = acc[fm][fn][r] * rinv;
                }
        }
    }
    __syncthreads();
}

// ---------------------------------------------------------------------------
// THE megakernel: whole decoder forward as one persistent cooperative grid.
// ---------------------------------------------------------------------------
__global__ __launch_bounds__(256) void mega_kernel(MegaArgs A, unsigned* bcnt,
                                                   unsigned* bgen) {
    __shared__ __align__(16) char smem[131072];   // forces 1 block/CU
    const int tid = threadIdx.x;
    const int bid = blockIdx.x;
    const int nblk = gridDim.x;
    const int gid = bid * 256 + tid;
    const int gstride = nblk * 256;

    // ---- phase 0: weight conversions + PE ----
    cvt_seg(A.Wq1, A.wq1, 1048576, gid, gstride);
    cvt_seg(A.Wk1, A.wk1, 1048576, gid, gstride);
    cvt_seg(A.Wv1, A.wv1, 1048576, gid, gstride);
    cvt_seg(A.Wo1, A.wo1, 1048576, gid, gstride);
    cvt_seg(A.Wq2, A.wq2, 1048576, gid, gstride);
    cvt_seg(A.Wk2, A.wk2, 1048576, gid, gstride);
    cvt_seg(A.Wv2, A.wv2, 1048576, gid, gstride);
    cvt_seg(A.Wo2, A.wo2, 1048576, gid, gstride);
    cvt_seg(A.W_ff1, A.wff1, 4194304, gid, gstride);
    cvt_seg(A.W_ff2, A.wff2, 4194304, gid, gstride);
    cvt_seg(A.ctx7, A.wctx, 65536, gid, gstride);
    pe_seg(A.x7, A.X, gid, gstride);
    gsync(bcnt, bgen);

    // ---- cross K2/V2 (once) + layer-0 QKV, one merged phase ----
    gemm_phase(smem, A.wctx, A.wk2, A.wv2, A.wv2, A.K2p, A.V2p, A.V2p,
               SEQN, D_EMB, D_EMB, 2, 2, bid, nblk);
    gemm_phase(smem, A.X, A.wq1, A.wk1, A.wv1, A.Qp, A.Kp, A.Vp,
               SEQN, D_EMB, D_EMB, 2, 3, bid, nblk);

    for (int l = 0; l < NLAYERS; ++l) {
        gsync(bcnt, bgen);
        for (int j = bid; j < SEQN; j += nblk)
            attn_job(smem, A.Qp, A.Kp, A.Vp, A.Att, 1, j);
        gsync(bcnt, bgen);
        gemm_phase(smem, A.Att, A.wo1, A.wo1, A.wo1, A.X2p, A.X2p, A.X2p,
                   SEQN, D_EMB, D_EMB, 2, 1, bid, nblk);
        gsync(bcnt, bgen);
        for (int j = bid; j < SEQN; j += nblk)
            ln_job<4>(smem, A.X2p, nullptr, A.g1, A.be1, A.X, j);
        gsync(bcnt, bgen);
        gemm_phase(smem, A.X, A.wq2, A.wq2, A.wq2, A.Qp, A.Qp, A.Qp,
                   SEQN, D_EMB, D_EMB, 2, 1, bid, nblk);
        gsync(bcnt, bgen);
        for (int j = bid; j < SEQN; j += nblk)
            attn_job(smem, A.Qp, A.K2p, A.V2p, A.Att, 0, j);
        gsync(bcnt, bgen);
        gemm_phase(smem, A.Att, A.wo2, A.wo2, A.wo2, A.X2p, A.X2p, A.X2p,
                   SEQN, D_EMB, D_EMB, 2, 1, bid, nblk);
        gsync(bcnt, bgen);
        for (int j = bid; j < SEQN; j += nblk)
            ln_job<4>(smem, A.X2p, nullptr, A.g2, A.be2, A.X, j);
        gsync(bcnt, bgen);
        gemm_phase(smem, A.X, A.wff1, A.wff1, A.wff1, A.FFp, A.FFp, A.FFp,
                   SEQN, DFF, D_EMB, 2, 1, bid, nblk);
        gsync(bcnt, bgen);
        biasrelu_phase(A.FFp, A.b_ff1, A.H, gid, gstride);
        gsync(bcnt, bgen);
        gemm_phase(smem, A.H, A.wff2, A.wff2, A.wff2, A.X2p, A.X2p, A.X2p,
                   SEQN, D_EMB, DFF, 4, 1, bid, nblk);
        gsync(bcnt, bgen);
        for (int j = bid; j < SEQN; j += nblk)
            ln_job<16>(smem, A.X2p, A.b_ff2, A.g3, A.be3, A.X, j);
        gsync(bcnt, bgen);
        if (l + 1 < NLAYERS)
            gemm_phase(smem, A.X, A.wq1, A.wk1, A.wv1, A.Qp, A.Kp, A.Vp,
                       SEQN, D_EMB, D_EMB, 2, 3, bid, nblk);
    }

    // ---- fused logits + sequence-axis softmax ----
    for (int j = bid; j < (VOCAB + 63) / 64; j += nblk)
        logits_job(smem, A.X, A.W_lin, A.out, j * 64);
}

// ---------------------------------------------------------------------------
extern "C" void kernel_launch(void* const* d_in, const int* in_sizes, int n_in,
                              void* d_out, int out_size, void* d_ws, size_t ws_size,
                              hipStream_t stream) {
    const float* x_in   = (const float*)d_in[0];
    const float* ctx_in = (const float*)d_in[1];

    const size_t W2 = (size_t)D_EMB * D_EMB;
    const size_t WF = (size_t)DFF * D_EMB;

    unsigned* bcnt = (unsigned*)d_ws;
    unsigned* bgen = bcnt + 1;
    char* p = (char*)d_ws + 256;

    MegaArgs a;
    a.x7   = x_in + (size_t)7 * TOKF;
    a.ctx7 = ctx_in + (size_t)7 * TOKF;
    a.Wq1 = (const float*)d_in[2];  a.Wk1 = (const float*)d_in[3];
    a.Wv1 = (const float*)d_in[4];  a.Wo1 = (const float*)d_in[5];
    a.Wq2 = (const float*)d_in[6];  a.Wk2 = (const float*)d_in[7];
    a.Wv2 = (const float*)d_in[8];  a.Wo2 = (const float*)d_in[9];
    a.W_ff1 = (const float*)d_in[10]; a.b_ff1 = (const float*)d_in[11];
    a.W_ff2 = (const float*)d_in[12]; a.b_ff2 = (const float*)d_in[13];
    a.g1 = (const float*)d_in[14]; a.be1 = (const float*)d_in[15];
    a.g2 = (const float*)d_in[16]; a.be2 = (const float*)d_in[17];
    a.g3 = (const float*)d_in[18]; a.be3 = (const float*)d_in[19];
    a.W_lin = (const float*)d_in[20];
    a.out = (float*)d_out;

    a.wq1 = (bf16*)p; p += W2 * 2;
    a.wk1 = (bf16*)p; p += W2 * 2;
    a.wv1 = (bf16*)p; p += W2 * 2;
    a.wo1 = (bf16*)p; p += W2 * 2;
    a.wq2 = (bf16*)p; p += W2 * 2;
    a.wk2 = (bf16*)p; p += W2 * 2;
    a.wv2 = (bf16*)p; p += W2 * 2;
    a.wo2 = (bf16*)p; p += W2 * 2;
    a.wff1 = (bf16*)p; p += WF * 2;
    a.wff2 = (bf16*)p; p += WF * 2;
    a.wctx = (bf16*)p; p += (size_t)TOKF * 2;
    a.X    = (bf16*)p; p += (size_t)TOKF * 2;
    a.Att  = (bf16*)p; p += (size_t)TOKF * 2;
    a.H    = (bf16*)p; p += (size_t)SEQN * DFF * 2;
    a.Qp  = (float*)p; p += (size_t)4 * TOKF * 4;
    a.Kp  = (float*)p; p += (size_t)4 * TOKF * 4;
    a.Vp  = (float*)p; p += (size_t)4 * TOKF * 4;
    a.X2p = (float*)p; p += (size_t)16 * TOKF * 4;
    a.K2p = (float*)p; p += (size_t)4 * TOKF * 4;
    a.V2p = (float*)p; p += (size_t)4 * TOKF * 4;
    a.FFp = (float*)p; p += (size_t)4 * SEQN * DFF * 4;

    static int nblk = 0;
    if (nblk == 0) {
        int dev = 0;
        hipGetDevice(&dev);
        hipDeviceProp_t prop{};
        hipGetDeviceProperties(&prop, dev);
        int maxb = 0;
        hipOccupancyMaxActiveBlocksPerMultiprocessor(&maxb, mega_kernel, 256, 0);
        if (maxb < 1) maxb = 1;
        long cap = (long)prop.multiProcessorCount * maxb;
        nblk = (int)((cap < 256) ? cap : 256);
        if (nblk < 1) nblk = 256;
    }

    hipMemsetAsync(d_ws, 0, 64, stream);   // zero barrier state (poison-proof)
    hipLaunchKernelGGL(mega_kernel, dim3(nblk), dim3(256), 0, stream,
                       a, bcnt, bgen);
}